// Round 3
// baseline (227.800 us; speedup 1.0000x reference)
//
#include <hip/hip_runtime.h>

#define B_ 32
#define T_ 2048
#define H_ 1024
#define S_ 8
#define V_ 32768
#define ROWS 256    // B_*S_
#define OUTO 8192   // S_*H_
#define NCHUNK 64
#define TCHUNK 32
#define NBLK 512    // dist grid = V_/64

typedef __attribute__((ext_vector_type(8))) short s16x8;
typedef __attribute__((ext_vector_type(8))) unsigned short u16x8;
typedef __attribute__((ext_vector_type(4))) float f32x4;

// ---------------- kernel 1: masked pooling partials ----------------
__global__ void pool_kernel(const float* __restrict__ hidden,
                            const int* __restrict__ mask,
                            float* __restrict__ part_pool,   // [NCHUNK][H_*B_] as [h][b]
                            int* __restrict__ cntpart) {     // [NCHUNK][B_]
  int b = blockIdx.x;
  int chunk = blockIdx.y;
  int t0 = chunk * TCHUNK;
  int h4 = threadIdx.x * 4;
  const float* base = hidden + ((size_t)b * T_ + t0) * H_ + h4;
  const int* mrow = mask + (size_t)b * T_ + t0;
  float a0 = 0.f, a1 = 0.f, a2 = 0.f, a3 = 0.f;
  int mcount = 0;
#pragma unroll 4
  for (int i = 0; i < TCHUNK; ++i) {
    int mi = mrow[i];
    float m = (float)mi;
    mcount += mi;
    float4 v = *reinterpret_cast<const float4*>(base + (size_t)i * H_);
    a0 += m * v.x; a1 += m * v.y; a2 += m * v.z; a3 += m * v.w;
  }
  float* pp = part_pool + (size_t)chunk * (H_ * B_);
  pp[(h4 + 0) * B_ + b] = a0;
  pp[(h4 + 1) * B_ + b] = a1;
  pp[(h4 + 2) * B_ + b] = a2;
  pp[(h4 + 3) * B_ + b] = a3;
  if (threadIdx.x == 0) cntpart[chunk * B_ + b] = mcount;
}

// ---------------- kernel 1b: reduce partials -> pooledT [h][b] ----------------
__global__ void pool_reduce_kernel(const float* __restrict__ part_pool,
                                   const int* __restrict__ cntpart,
                                   float* __restrict__ pooledT,
                                   int* __restrict__ cnt) {
  int g = blockIdx.x * 256 + threadIdx.x;
  float s = 0.f;
  for (int c = 0; c < NCHUNK; ++c) s += part_pool[(size_t)c * (H_ * B_) + g];
  pooledT[g] = s;
  if (g < B_) {
    int cs = 0;
    for (int c = 0; c < NCHUNK; ++c) cs += cntpart[c * B_ + g];
    cnt[g] = cs;
  }
}

// ---------------- kernel 2: pre_q = pooled @ W^T ----------------
__global__ void proj_kernel(const float* __restrict__ Wp,
                            const float* __restrict__ pooledT,
                            const int* __restrict__ cnt,
                            float* __restrict__ preq) {
  int t = threadIdx.x;
  int olocal = t >> 5;
  int o = blockIdx.x * 8 + olocal;
  int b = t & 31;
  const float* wrow = Wp + (size_t)o * H_;
  float acc = 0.f;
#pragma unroll 4
  for (int k = 0; k < H_; k += 4) {
    float4 w4 = *reinterpret_cast<const float4*>(wrow + k);
    float p0 = pooledT[(k + 0) * B_ + b];
    float p1 = pooledT[(k + 1) * B_ + b];
    float p2 = pooledT[(k + 2) * B_ + b];
    float p3 = pooledT[(k + 3) * B_ + b];
    acc += w4.x * p0 + w4.y * p1 + w4.z * p2 + w4.w * p3;
  }
  float denom = fmaxf((float)cnt[b], 1.0f);
  float val = acc / denom;
  __shared__ float xch[8][32];
  xch[olocal][b] = val;
  __syncthreads();
  int b2 = t >> 3, j = t & 7;
  preq[(size_t)b2 * OUTO + blockIdx.x * 8 + j] = xch[j][b2];
}

// bf16 split: x ~= hi + lo (RNE hi, truncated lo)
__device__ __forceinline__ void bsplit(float x, unsigned short& h, unsigned short& s) {
  unsigned int u = __float_as_uint(x);
  unsigned int r = u + 0x7fffu + ((u >> 16) & 1u);
  h = (unsigned short)(r >> 16);
  float hf = __uint_as_float(r & 0xffff0000u);
  float lo = x - hf;
  s = (unsigned short)(__float_as_uint(lo) >> 16);
}

// ---------------- kernel 2b: split preq into MFMA-layout bf16 image + xnorm ----------------
// A_img layout (ushort units): [ks 0..31] { hi[256][32], lo[256][32] }  (16384 ushort per ks)
__global__ void aprep_kernel(const float* __restrict__ preq,
                             unsigned short* __restrict__ A_img,
                             float* __restrict__ xnorm) {
  int row = blockIdx.x;
  int t = threadIdx.x;            // 256 threads, 4 consecutive k each
  int k0 = 4 * t;
  int ks = k0 >> 5, kk = k0 & 31;
  float4 v = reinterpret_cast<const float4*>(preq + (size_t)row * H_)[t];
  float xv[4] = {v.x, v.y, v.z, v.w};
  unsigned short hv[4], lv[4];
  float s = 0.f;
#pragma unroll
  for (int i = 0; i < 4; ++i) { s += xv[i] * xv[i]; bsplit(xv[i], hv[i], lv[i]); }
  size_t base = (size_t)ks * 16384 + (size_t)row * 32 + kk;
  *reinterpret_cast<ushort4*>(&A_img[base])        = make_ushort4(hv[0], hv[1], hv[2], hv[3]);
  *reinterpret_cast<ushort4*>(&A_img[base + 8192]) = make_ushort4(lv[0], lv[1], lv[2], lv[3]);
#pragma unroll
  for (int off = 1; off < 64; off <<= 1) s += __shfl_xor(s, off);
  __shared__ float ps[4];
  if ((t & 63) == 0) ps[t >> 6] = s;
  __syncthreads();
  if (t == 0) xnorm[row] = ps[0] + ps[1] + ps[2] + ps[3];
}

// ---------------- kernel 3: split-bf16 MFMA distance GEMM + logits + block argmax ----------------
// 256 threads (4 waves), N-tile 64, grid 512 -> 2 independent blocks/CU for phase overlap.
// One barrier per K-step via double-buffered Bs (read cur / write cur^1).
__global__ __launch_bounds__(256) void dist_kernel(
    const unsigned short* __restrict__ A_img, const float* __restrict__ codebook,
    const float* __restrict__ xnorm, float* __restrict__ logits,
    float* __restrict__ pscore, int* __restrict__ pidx) {
  __shared__ __align__(16) unsigned short Bs[2][2][64][40];  // [buf][hi/lo][n][k] pad 40
  __shared__ float cn[64];
  __shared__ float xns[256];

  const int t = threadIdx.x;
  const int l = t & 63;
  const int w = t >> 6;           // wave 0..3
  const int blk = blockIdx.x;
  const int v0 = blk * 64;
  const int m0 = w * 64;          // each wave owns 64 rows x 64 cols
  const int lr = l & 15, lq = l >> 4;

  xns[t] = xnorm[t];

  const int sn = t >> 2;          // staged codebook row 0..63
  const int sk = (t & 3) * 8;     // k offset within 32
  const float* cbp = codebook + (size_t)(v0 + sn) * H_ + sk;
  float csq = 0.f;

  f32x4 acc[4][4];
#pragma unroll
  for (int i = 0; i < 4; ++i)
#pragma unroll
    for (int j = 0; j < 4; ++j) acc[i][j] = (f32x4){0.f, 0.f, 0.f, 0.f};

  // prologue: convert ks=0 into buf 0, prefetch ks=1
  {
    float4 c0 = *reinterpret_cast<const float4*>(cbp);
    float4 c1 = *reinterpret_cast<const float4*>(cbp + 4);
    float xv[8] = {c0.x, c0.y, c0.z, c0.w, c1.x, c1.y, c1.z, c1.w};
    u16x8 hv, lv;
#pragma unroll
    for (int i = 0; i < 8; ++i) {
      float x = xv[i];
      csq += x * x;
      unsigned short hh, ll;
      bsplit(x, hh, ll);
      hv[i] = hh; lv[i] = ll;
    }
    *reinterpret_cast<u16x8*>(&Bs[0][0][sn][sk]) = hv;
    *reinterpret_cast<u16x8*>(&Bs[0][1][sn][sk]) = lv;
  }
  float4 n0 = *reinterpret_cast<const float4*>(cbp + 32);
  float4 n1 = *reinterpret_cast<const float4*>(cbp + 36);
  __syncthreads();

  int cur = 0;
  for (int ks = 0; ks < 32; ++ks) {
    // A fragments: coalesced 16B/lane global loads (1MB image, L2-hot)
    const unsigned short* ab = A_img + (size_t)ks * 16384;
    s16x8 ah[4], al[4], bh[4], bl[4];
#pragma unroll
    for (int mt = 0; mt < 4; ++mt) {
      const unsigned short* p = ab + (size_t)(m0 + mt * 16 + lr) * 32 + lq * 8;
      ah[mt] = *reinterpret_cast<const s16x8*>(p);
      al[mt] = *reinterpret_cast<const s16x8*>(p + 8192);
    }
    // B fragments from current buffer
#pragma unroll
    for (int nt = 0; nt < 4; ++nt) {
      bh[nt] = *reinterpret_cast<const s16x8*>(&Bs[cur][0][nt * 16 + lr][lq * 8]);
      bl[nt] = *reinterpret_cast<const s16x8*>(&Bs[cur][1][nt * 16 + lr][lq * 8]);
    }
    // convert next K-step (loaded 1 iteration ago) into the alternate buffer
    if (ks < 31) {
      float xv[8] = {n0.x, n0.y, n0.z, n0.w, n1.x, n1.y, n1.z, n1.w};
      u16x8 hv, lv;
#pragma unroll
      for (int i = 0; i < 8; ++i) {
        float x = xv[i];
        csq += x * x;
        unsigned short hh, ll;
        bsplit(x, hh, ll);
        hv[i] = hh; lv[i] = ll;
      }
      *reinterpret_cast<u16x8*>(&Bs[cur ^ 1][0][sn][sk]) = hv;
      *reinterpret_cast<u16x8*>(&Bs[cur ^ 1][1][sn][sk]) = lv;
    }
    // issue loads 2 K-steps ahead (arrive well before their convert)
    if (ks < 30) {
      n0 = *reinterpret_cast<const float4*>(cbp + (ks + 2) * 32);
      n1 = *reinterpret_cast<const float4*>(cbp + (ks + 2) * 32 + 4);
    }
    __syncthreads();
#pragma unroll
    for (int mt = 0; mt < 4; ++mt)
#pragma unroll
      for (int nt = 0; nt < 4; ++nt) {
        acc[mt][nt] = __builtin_amdgcn_mfma_f32_16x16x32_bf16(ah[mt], bh[nt], acc[mt][nt], 0, 0, 0);
        acc[mt][nt] = __builtin_amdgcn_mfma_f32_16x16x32_bf16(ah[mt], bl[nt], acc[mt][nt], 0, 0, 0);
        acc[mt][nt] = __builtin_amdgcn_mfma_f32_16x16x32_bf16(al[mt], bh[nt], acc[mt][nt], 0, 0, 0);
      }
    cur ^= 1;
  }

  // ||c||^2: reduce the 4 k-offset threads (consecutive lanes) of each staged row
  csq += __shfl_xor(csq, 1);
  csq += __shfl_xor(csq, 2);
  if ((t & 3) == 0) cn[sn] = csq;
  __syncthreads();

  // epilogue: logits + per-row best over this block's 64 cols (each wave owns its rows)
  const float NEG = -3.402823466e38f;
#pragma unroll
  for (int mt = 0; mt < 4; ++mt) {
#pragma unroll
    for (int r = 0; r < 4; ++r) {
      int row = m0 + mt * 16 + lq * 4 + r;
      float xn = xns[row];
      float bs = NEG; int bix = 0;
#pragma unroll
      for (int nt = 0; nt < 4; ++nt) {
        int col = nt * 16 + lr;
        float sc = 2.f * acc[mt][nt][r] - cn[col];
        logits[(size_t)row * V_ + v0 + col] = sc - xn;
        if (sc > bs) { bs = sc; bix = v0 + col; }   // nt ascending => first-max tie-break
      }
#pragma unroll
      for (int off = 1; off < 16; off <<= 1) {      // reduce within 16-lane (same-row) group
        float os = __shfl_xor(bs, off);
        int oi = __shfl_xor(bix, off);
        if (os > bs || (os == bs && oi < bix)) { bs = os; bix = oi; }
      }
      if (lr == 0) {
        pscore[(size_t)row * NBLK + blk] = bs;
        pidx[(size_t)row * NBLK + blk] = bix;
      }
    }
  }
}

// ---------------- kernel 4: per-row argmax over blocks, gather, quantized, loss partial ----------------
__global__ void finalize_kernel(const float* __restrict__ preq,
                                const float* __restrict__ codebook,
                                const float* __restrict__ pscore,
                                const int* __restrict__ pidx,
                                float* __restrict__ out_idx,
                                float* __restrict__ out_quant,
                                float* __restrict__ lsum) {
  int row = blockIdx.x;
  int t = threadIdx.x;
  float bs = -3.402823466e38f; int bi = 0x7fffffff;
  for (int p = t; p < NBLK; p += 256) {
    float s = pscore[(size_t)row * NBLK + p];
    int ix = pidx[(size_t)row * NBLK + p];
    if (s > bs || (s == bs && ix < bi)) { bs = s; bi = ix; }
  }
#pragma unroll
  for (int off = 1; off < 64; off <<= 1) {
    float os = __shfl_xor(bs, off);
    int oi = __shfl_xor(bi, off);
    if (os > bs || (os == bs && oi < bi)) { bs = os; bi = oi; }
  }
  __shared__ float ss[4]; __shared__ int si[4]; __shared__ int fidx;
  if ((t & 63) == 0) { ss[t >> 6] = bs; si[t >> 6] = bi; }
  __syncthreads();
  if (t == 0) {
    float b0 = ss[0]; int i0 = si[0];
    for (int wv = 1; wv < 4; ++wv)
      if (ss[wv] > b0 || (ss[wv] == b0 && si[wv] < i0)) { b0 = ss[wv]; i0 = si[wv]; }
    fidx = i0;
    out_idx[row] = (float)i0;
  }
  __syncthreads();
  int idx = fidx;
  float4 e = reinterpret_cast<const float4*>(codebook + (size_t)idx * H_)[t];
  float4 p = reinterpret_cast<const float4*>(preq + (size_t)row * H_)[t];
  float4 q;
  q.x = p.x + (e.x - p.x); q.y = p.y + (e.y - p.y);
  q.z = p.z + (e.z - p.z); q.w = p.w + (e.w - p.w);
  reinterpret_cast<float4*>(out_quant)[row * 256 + t] = q;
  float dx = p.x - e.x, dy = p.y - e.y, dz = p.z - e.z, dw = p.w - e.w;
  float ls = dx * dx + dy * dy + dz * dz + dw * dw;
#pragma unroll
  for (int off = 1; off < 64; off <<= 1) ls += __shfl_xor(ls, off);
  __shared__ float lss[4];
  if ((t & 63) == 0) lss[t >> 6] = ls;
  __syncthreads();
  if (t == 0) lsum[row] = lss[0] + lss[1] + lss[2] + lss[3];
}

// ---------------- kernel 5: final losses ----------------
__global__ void loss_kernel(const float* __restrict__ lsum, float* __restrict__ out_loss) {
  int t = threadIdx.x;
  float s = lsum[t];
#pragma unroll
  for (int off = 1; off < 64; off <<= 1) s += __shfl_xor(s, off);
  __shared__ float a[4];
  if ((t & 63) == 0) a[t >> 6] = s;
  __syncthreads();
  if (t == 0) {
    float lv = (a[0] + a[1] + a[2] + a[3]) / (float)(ROWS * H_);
    out_loss[0] = lv; out_loss[1] = lv;
  }
}

extern "C" void kernel_launch(void* const* d_in, const int* in_sizes, int n_in,
                              void* d_out, int out_size, void* d_ws, size_t ws_size,
                              hipStream_t stream) {
  (void)in_sizes; (void)n_in; (void)out_size; (void)ws_size;
  const float* hidden   = (const float*)d_in[0];
  const int* mask       = (const int*)d_in[1];
  const float* Wp       = (const float*)d_in[2];
  const float* codebook = (const float*)d_in[3];

  float* out = (float*)d_out;
  float* out_logits = out;                        // 8388608
  float* out_idx    = out + 8388608;              // 256
  float* out_preq   = out_idx + 256;              // 262144
  float* out_quant  = out_preq + 262144;          // 262144
  float* out_loss   = out_quant + 262144;         // 2

  // Early scratch inside logits region (fully overwritten by dist_kernel later).
  float* part_pool = out_logits;                   // 64*32768 = 2097152 floats
  int*   cntpart   = (int*)(out_logits + 2097152); // 2048
  float* pooledT   = out_logits + 2099200;         // 32768
  int*   cnt       = (int*)(out_logits + 2131968); // 32

  // d_ws scratch (~2.1 MB)
  float* ws     = (float*)d_ws;
  float* xnorm  = ws;                              // 256
  float* pscore = ws + 256;                        // 256*512
  int*   pidx   = (int*)(ws + 131328);             // 256*512
  float* lsum   = ws + 262400;                     // 256
  unsigned short* A_img = (unsigned short*)(ws + 262656);  // 1 MB

  pool_kernel<<<dim3(B_, NCHUNK), 256, 0, stream>>>(hidden, mask, part_pool, cntpart);
  pool_reduce_kernel<<<128, 256, 0, stream>>>(part_pool, cntpart, pooledT, cnt);
  proj_kernel<<<1024, 256, 0, stream>>>(Wp, pooledT, cnt, out_preq);
  aprep_kernel<<<ROWS, 256, 0, stream>>>(out_preq, A_img, xnorm);
  dist_kernel<<<NBLK, 256, 0, stream>>>(A_img, codebook, xnorm, out_logits, pscore, pidx);
  finalize_kernel<<<ROWS, 256, 0, stream>>>(out_preq, codebook, pscore, pidx, out_idx, out_quant, lsum);
  loss_kernel<<<1, 256, 0, stream>>>(lsum, out_loss);
}

// Round 4
// 221.764 us; speedup vs baseline: 1.0272x; 1.0272x over previous
//
#include <hip/hip_runtime.h>

#define B_ 32
#define T_ 2048
#define H_ 1024
#define S_ 8
#define V_ 32768
#define ROWS 256    // B_*S_
#define OUTO 8192   // S_*H_
#define NCHUNK 64
#define TCHUNK 32
#define NCB 256     // dist col-blocks = V_/128

typedef __attribute__((ext_vector_type(8))) short s16x8;
typedef __attribute__((ext_vector_type(8))) unsigned short u16x8;
typedef __attribute__((ext_vector_type(4))) float f32x4;

// async global->LDS, 16B per lane (dest = wave-uniform base + lane*16)
__device__ __forceinline__ void gl_lds16(const void* gsrc, void* ldst) {
  __builtin_amdgcn_global_load_lds(
      (const __attribute__((address_space(1))) unsigned int*)gsrc,
      (__attribute__((address_space(3))) unsigned int*)ldst, 16, 0, 0);
}

// ---------------- kernel 1: masked pooling partials ----------------
__global__ void pool_kernel(const float* __restrict__ hidden,
                            const int* __restrict__ mask,
                            float* __restrict__ part_pool,   // [NCHUNK][B_][H_]
                            int* __restrict__ cntpart) {     // [NCHUNK][B_]
  int b = blockIdx.x;
  int chunk = blockIdx.y;
  int t0 = chunk * TCHUNK;
  int h4 = threadIdx.x * 4;
  const float* base = hidden + ((size_t)b * T_ + t0) * H_ + h4;
  const int* mrow = mask + (size_t)b * T_ + t0;
  float a0 = 0.f, a1 = 0.f, a2 = 0.f, a3 = 0.f;
  int mcount = 0;
#pragma unroll 4
  for (int i = 0; i < TCHUNK; ++i) {
    int mi = mrow[i];
    float m = (float)mi;
    mcount += mi;
    float4 v = *reinterpret_cast<const float4*>(base + (size_t)i * H_);
    a0 += m * v.x; a1 += m * v.y; a2 += m * v.z; a3 += m * v.w;
  }
  float* pp = part_pool + ((size_t)chunk * B_ + b) * H_ + h4;
  *reinterpret_cast<float4*>(pp) = make_float4(a0, a1, a2, a3);
  if (threadIdx.x == 0) cntpart[chunk * B_ + b] = mcount;
}

// ---------------- kernel 1b: reduce partials -> pooledT [h][b] ----------------
__global__ void pool_reduce_kernel(const float* __restrict__ part_pool,
                                   const int* __restrict__ cntpart,
                                   float* __restrict__ pooledT,
                                   int* __restrict__ cnt) {
  int g = blockIdx.x * 256 + threadIdx.x;   // g = b*1024 + h
  float s = 0.f;
  for (int c = 0; c < NCHUNK; ++c) s += part_pool[(size_t)c * (H_ * B_) + g];
  int b = g >> 10, h = g & 1023;
  pooledT[h * B_ + b] = s;
  if (g < B_) {
    int cs = 0;
    for (int c = 0; c < NCHUNK; ++c) cs += cntpart[c * B_ + g];
    cnt[g] = cs;
  }
}

// ---------------- kernel 2: pre_q = pooled @ W^T ----------------
__global__ void proj_kernel(const float* __restrict__ Wp,
                            const float* __restrict__ pooledT,
                            const int* __restrict__ cnt,
                            float* __restrict__ preq) {
  int t = threadIdx.x;
  int olocal = t >> 5;
  int o = blockIdx.x * 8 + olocal;
  int b = t & 31;
  const float* wrow = Wp + (size_t)o * H_;
  float acc = 0.f;
#pragma unroll 4
  for (int k = 0; k < H_; k += 4) {
    float4 w4 = *reinterpret_cast<const float4*>(wrow + k);
    float p0 = pooledT[(k + 0) * B_ + b];
    float p1 = pooledT[(k + 1) * B_ + b];
    float p2 = pooledT[(k + 2) * B_ + b];
    float p3 = pooledT[(k + 3) * B_ + b];
    acc += w4.x * p0 + w4.y * p1 + w4.z * p2 + w4.w * p3;
  }
  float denom = fmaxf((float)cnt[b], 1.0f);
  float val = acc / denom;
  __shared__ float xch[8][32];
  xch[olocal][b] = val;
  __syncthreads();
  int b2 = t >> 3, j = t & 7;
  preq[(size_t)b2 * OUTO + blockIdx.x * 8 + j] = xch[j][b2];
}

// bf16 split: x ~= hi + lo (RNE hi, truncated lo)
__device__ __forceinline__ void bsplit(float x, unsigned short& h, unsigned short& s) {
  unsigned int u = __float_as_uint(x);
  unsigned int r = u + 0x7fffu + ((u >> 16) & 1u);
  h = (unsigned short)(r >> 16);
  float hf = __uint_as_float(r & 0xffff0000u);
  float lo = x - hf;
  s = (unsigned short)(__float_as_uint(lo) >> 16);
}

// ---------------- kernel 2b: split preq into MFMA-layout bf16 image + xnorm ----------------
// A_img (ushort): [ks 0..31] { hi[256][32], lo[256][32] }  (16384 ushort = 32KB per ks)
__global__ void aprep_kernel(const float* __restrict__ preq,
                             unsigned short* __restrict__ A_img,
                             float* __restrict__ xnorm) {
  int row = blockIdx.x;
  int t = threadIdx.x;
  int k0 = 4 * t;
  int ks = k0 >> 5, kk = k0 & 31;
  float4 v = reinterpret_cast<const float4*>(preq + (size_t)row * H_)[t];
  float xv[4] = {v.x, v.y, v.z, v.w};
  unsigned short hv[4], lv[4];
  float s = 0.f;
#pragma unroll
  for (int i = 0; i < 4; ++i) { s += xv[i] * xv[i]; bsplit(xv[i], hv[i], lv[i]); }
  size_t base = (size_t)ks * 16384 + (size_t)row * 32 + kk;
  *reinterpret_cast<ushort4*>(&A_img[base])        = make_ushort4(hv[0], hv[1], hv[2], hv[3]);
  *reinterpret_cast<ushort4*>(&A_img[base + 8192]) = make_ushort4(lv[0], lv[1], lv[2], lv[3]);
#pragma unroll
  for (int off = 1; off < 64; off <<= 1) s += __shfl_xor(s, off);
  __shared__ float ps[4];
  if ((t & 63) == 0) ps[t >> 6] = s;
  __syncthreads();
  if (t == 0) xnorm[row] = ps[0] + ps[1] + ps[2] + ps[3];
}

// ---------------- kernel 3: split-bf16 MFMA distance GEMM ----------------
// BM=256 (all rows), BN=128, BK=32. 512 threads = 8 waves (4 row-groups x 2 col-halves).
// Grid 256 = 1 block/CU; codebook read exactly once. A staged async via global_load_lds
// (double-buffered LDS); B f32 prefetched to regs at iter top, converted to hi/lo bf16
// LDS after the MFMA block. One barrier per K-step.
__global__ __launch_bounds__(512, 2) void dist_kernel(
    const unsigned short* __restrict__ A_img, const float* __restrict__ codebook,
    const float* __restrict__ xnorm, float* __restrict__ logits,
    float* __restrict__ pscore, int* __restrict__ pidx) {
  __shared__ __align__(16) unsigned short Asm[2][16384];    // 64 KB: [buf]{hi[256][32],lo[256][32]}
  __shared__ __align__(16) unsigned short Bs[2][2][128][40];// 40 KB: [buf][hi/lo][col][k] pad 40
  __shared__ float cn[128];
  __shared__ float xns[256];
  __shared__ float bwv[2][256];
  __shared__ int   bwi[2][256];

  const int t = threadIdx.x;        // 0..511
  const int l = t & 63;
  const int w = t >> 6;             // wave 0..7
  const int cb = w & 1;             // col half (0..1)
  const int m0 = (w >> 1) * 64;     // row group (0,64,128,192)
  const int lr = l & 15, lq = l >> 4;
  const int blk = blockIdx.x;
  const int v0 = blk * 128;

  if (t < 256) xns[t] = xnorm[t];

  const int sn = t >> 2;            // staged codebook row 0..127
  const int sk = (t & 3) * 8;       // k offset within 32
  const float* cbp = codebook + (size_t)(v0 + sn) * H_ + sk;
  float csq = 0.f;

  f32x4 acc[4][4];
#pragma unroll
  for (int i = 0; i < 4; ++i)
#pragma unroll
    for (int j = 0; j < 4; ++j) acc[i][j] = (f32x4){0.f, 0.f, 0.f, 0.f};

  const char* Abase = (const char*)A_img;

  // ---- prologue: stage A(0) async; load+convert B(0) ----
#pragma unroll
  for (int j = 0; j < 4; ++j) {
    int c = w * 4 + j;
    gl_lds16(Abase + (size_t)c * 1024 + (size_t)l * 16, &Asm[0][c * 512]);
  }
  float4 r0 = *reinterpret_cast<const float4*>(cbp);
  float4 r1 = *reinterpret_cast<const float4*>(cbp + 4);
  {
    float xv[8] = {r0.x, r0.y, r0.z, r0.w, r1.x, r1.y, r1.z, r1.w};
    u16x8 hv, lv;
#pragma unroll
    for (int i = 0; i < 8; ++i) {
      float x = xv[i];
      csq += x * x;
      unsigned short hh, ll;
      bsplit(x, hh, ll);
      hv[i] = hh; lv[i] = ll;
    }
    *reinterpret_cast<u16x8*>(&Bs[0][0][sn][sk]) = hv;
    *reinterpret_cast<u16x8*>(&Bs[0][1][sn][sk]) = lv;
  }
  __syncthreads();

  int cur = 0;
#pragma unroll 2
  for (int ks = 0; ks < 32; ++ks) {
    // issue next-step loads at the top (A async -> LDS buf^1; B f32 -> regs)
    if (ks < 31) {
#pragma unroll
      for (int j = 0; j < 4; ++j) {
        int c = w * 4 + j;
        gl_lds16(Abase + (size_t)(ks + 1) * 32768 + (size_t)c * 1024 + (size_t)l * 16,
                 &Asm[cur ^ 1][c * 512]);
      }
      r0 = *reinterpret_cast<const float4*>(cbp + (ks + 1) * 32);
      r1 = *reinterpret_cast<const float4*>(cbp + (ks + 1) * 32 + 4);
    }
    // fragments from current buffers
    s16x8 ah[4], al[4], bh[4], bl[4];
#pragma unroll
    for (int mt = 0; mt < 4; ++mt) {
      const unsigned short* p = &Asm[cur][(m0 + mt * 16 + lr) * 32 + lq * 8];
      ah[mt] = *reinterpret_cast<const s16x8*>(p);
      al[mt] = *reinterpret_cast<const s16x8*>(p + 8192);
    }
#pragma unroll
    for (int nt = 0; nt < 4; ++nt) {
      bh[nt] = *reinterpret_cast<const s16x8*>(&Bs[cur][0][cb * 64 + nt * 16 + lr][lq * 8]);
      bl[nt] = *reinterpret_cast<const s16x8*>(&Bs[cur][1][cb * 64 + nt * 16 + lr][lq * 8]);
    }
#pragma unroll
    for (int mt = 0; mt < 4; ++mt)
#pragma unroll
      for (int nt = 0; nt < 4; ++nt) {
        acc[mt][nt] = __builtin_amdgcn_mfma_f32_16x16x32_bf16(ah[mt], bh[nt], acc[mt][nt], 0, 0, 0);
        acc[mt][nt] = __builtin_amdgcn_mfma_f32_16x16x32_bf16(ah[mt], bl[nt], acc[mt][nt], 0, 0, 0);
        acc[mt][nt] = __builtin_amdgcn_mfma_f32_16x16x32_bf16(al[mt], bh[nt], acc[mt][nt], 0, 0, 0);
      }
    // convert next-step B (regs loaded at top; MFMA block covered the HBM latency)
    if (ks < 31) {
      float xv[8] = {r0.x, r0.y, r0.z, r0.w, r1.x, r1.y, r1.z, r1.w};
      u16x8 hv, lv;
#pragma unroll
      for (int i = 0; i < 8; ++i) {
        float x = xv[i];
        csq += x * x;
        unsigned short hh, ll;
        bsplit(x, hh, ll);
        hv[i] = hh; lv[i] = ll;
      }
      *reinterpret_cast<u16x8*>(&Bs[cur ^ 1][0][sn][sk]) = hv;
      *reinterpret_cast<u16x8*>(&Bs[cur ^ 1][1][sn][sk]) = lv;
    }
    __syncthreads();   // compiler drains vmcnt here -> A(ks+1) complete, B LDS visible
    cur ^= 1;
  }

  // ||c||^2: reduce the 4 k-offset threads (consecutive lanes) of each staged row
  csq += __shfl_xor(csq, 1);
  csq += __shfl_xor(csq, 2);
  if ((t & 3) == 0) cn[sn] = csq;
  __syncthreads();

  // epilogue: logits + per-row best over this block's 128 cols
  const float NEG = -3.402823466e38f;
#pragma unroll
  for (int mt = 0; mt < 4; ++mt) {
#pragma unroll
    for (int r = 0; r < 4; ++r) {
      int row = m0 + mt * 16 + lq * 4 + r;
      float xn = xns[row];
      float bs = NEG; int bix = 0;
#pragma unroll
      for (int nt = 0; nt < 4; ++nt) {
        int col = cb * 64 + nt * 16 + lr;
        float sc = 2.f * acc[mt][nt][r] - cn[col];
        logits[(size_t)row * V_ + v0 + col] = sc - xn;
        if (sc > bs) { bs = sc; bix = v0 + col; }   // nt ascending => first-max tie-break
      }
#pragma unroll
      for (int off = 1; off < 16; off <<= 1) {      // reduce within 16-lane (same-row) group
        float os = __shfl_xor(bs, off);
        int oi = __shfl_xor(bix, off);
        if (os > bs || (os == bs && oi < bix)) { bs = os; bix = oi; }
      }
      if (lr == 0) { bwv[cb][row] = bs; bwi[cb][row] = bix; }
    }
  }
  __syncthreads();
  if (t < 256) {
    float b0 = bwv[0][t]; int i0 = bwi[0][t];
    float b1 = bwv[1][t]; int i1 = bwi[1][t];
    if (b1 > b0 || (b1 == b0 && i1 < i0)) { b0 = b1; i0 = i1; }
    pscore[(size_t)t * NCB + blk] = b0;
    pidx[(size_t)t * NCB + blk] = i0;
  }
}

// ---------------- kernel 4: per-row argmax over blocks, gather, quantized, loss partial ----------------
__global__ void finalize_kernel(const float* __restrict__ preq,
                                const float* __restrict__ codebook,
                                const float* __restrict__ pscore,
                                const int* __restrict__ pidx,
                                float* __restrict__ out_idx,
                                float* __restrict__ out_quant,
                                float* __restrict__ lsum) {
  int row = blockIdx.x;
  int t = threadIdx.x;
  float bs = -3.402823466e38f; int bi = 0x7fffffff;
  for (int p = t; p < NCB; p += 256) {
    float s = pscore[(size_t)row * NCB + p];
    int ix = pidx[(size_t)row * NCB + p];
    if (s > bs || (s == bs && ix < bi)) { bs = s; bi = ix; }
  }
#pragma unroll
  for (int off = 1; off < 64; off <<= 1) {
    float os = __shfl_xor(bs, off);
    int oi = __shfl_xor(bi, off);
    if (os > bs || (os == bs && oi < bi)) { bs = os; bi = oi; }
  }
  __shared__ float ss[4]; __shared__ int si[4]; __shared__ int fidx;
  if ((t & 63) == 0) { ss[t >> 6] = bs; si[t >> 6] = bi; }
  __syncthreads();
  if (t == 0) {
    float b0 = ss[0]; int i0 = si[0];
    for (int wv = 1; wv < 4; ++wv)
      if (ss[wv] > b0 || (ss[wv] == b0 && si[wv] < i0)) { b0 = ss[wv]; i0 = si[wv]; }
    fidx = i0;
    out_idx[row] = (float)i0;
  }
  __syncthreads();
  int idx = fidx;
  float4 e = reinterpret_cast<const float4*>(codebook + (size_t)idx * H_)[t];
  float4 p = reinterpret_cast<const float4*>(preq + (size_t)row * H_)[t];
  float4 q;
  q.x = p.x + (e.x - p.x); q.y = p.y + (e.y - p.y);
  q.z = p.z + (e.z - p.z); q.w = p.w + (e.w - p.w);
  reinterpret_cast<float4*>(out_quant)[row * 256 + t] = q;
  float dx = p.x - e.x, dy = p.y - e.y, dz = p.z - e.z, dw = p.w - e.w;
  float ls = dx * dx + dy * dy + dz * dz + dw * dw;
#pragma unroll
  for (int off = 1; off < 64; off <<= 1) ls += __shfl_xor(ls, off);
  __shared__ float lss[4];
  if ((t & 63) == 0) lss[t >> 6] = ls;
  __syncthreads();
  if (t == 0) lsum[row] = lss[0] + lss[1] + lss[2] + lss[3];
}

// ---------------- kernel 5: final losses ----------------
__global__ void loss_kernel(const float* __restrict__ lsum, float* __restrict__ out_loss) {
  int t = threadIdx.x;
  float s = lsum[t];
#pragma unroll
  for (int off = 1; off < 64; off <<= 1) s += __shfl_xor(s, off);
  __shared__ float a[4];
  if ((t & 63) == 0) a[t >> 6] = s;
  __syncthreads();
  if (t == 0) {
    float lv = (a[0] + a[1] + a[2] + a[3]) / (float)(ROWS * H_);
    out_loss[0] = lv; out_loss[1] = lv;
  }
}

extern "C" void kernel_launch(void* const* d_in, const int* in_sizes, int n_in,
                              void* d_out, int out_size, void* d_ws, size_t ws_size,
                              hipStream_t stream) {
  (void)in_sizes; (void)n_in; (void)out_size; (void)ws_size;
  const float* hidden   = (const float*)d_in[0];
  const int* mask       = (const int*)d_in[1];
  const float* Wp       = (const float*)d_in[2];
  const float* codebook = (const float*)d_in[3];

  float* out = (float*)d_out;
  float* out_logits = out;                        // 8388608
  float* out_idx    = out + 8388608;              // 256
  float* out_preq   = out_idx + 256;              // 262144
  float* out_quant  = out_preq + 262144;          // 262144
  float* out_loss   = out_quant + 262144;         // 2

  // Early scratch inside logits region (fully overwritten by dist_kernel later).
  float* part_pool = out_logits;                   // 64*32*1024 = 2097152 floats
  int*   cntpart   = (int*)(out_logits + 2097152); // 2048
  float* pooledT   = out_logits + 2099200;         // 32768
  int*   cnt       = (int*)(out_logits + 2131968); // 32

  // d_ws scratch (~1.6 MB)
  float* ws     = (float*)d_ws;
  float* xnorm  = ws;                              // 256
  float* pscore = ws + 256;                        // 256*256
  int*   pidx   = (int*)(ws + 256 + 65536);        // 256*256
  float* lsum   = ws + 131328;                     // 256
  unsigned short* A_img = (unsigned short*)(ws + 131584);  // 1 MB

  pool_kernel<<<dim3(B_, NCHUNK), 256, 0, stream>>>(hidden, mask, part_pool, cntpart);
  pool_reduce_kernel<<<128, 256, 0, stream>>>(part_pool, cntpart, pooledT, cnt);
  proj_kernel<<<1024, 256, 0, stream>>>(Wp, pooledT, cnt, out_preq);
  aprep_kernel<<<ROWS, 256, 0, stream>>>(out_preq, A_img, xnorm);
  dist_kernel<<<NCB, 512, 0, stream>>>(A_img, codebook, xnorm, out_logits, pscore, pidx);
  finalize_kernel<<<ROWS, 256, 0, stream>>>(out_preq, codebook, pscore, pidx, out_idx, out_quant, lsum);
  loss_kernel<<<1, 256, 0, stream>>>(lsum, out_loss);
}

// Round 5
// 217.515 us; speedup vs baseline: 1.0473x; 1.0195x over previous
//
#include <hip/hip_runtime.h>
#include <hip/hip_bf16.h>

#define B_ 32
#define T_ 2048
#define H_ 1024
#define S_ 8
#define V_ 32768
#define ROWS 256    // B_*S_
#define OUTO 8192   // S_*H_
#define NCHUNK 64
#define TCHUNK 32
#define NCB 256     // dist col-blocks = V_/128

typedef __attribute__((ext_vector_type(8))) short s16x8;
typedef __attribute__((ext_vector_type(8))) unsigned short u16x8;
typedef __attribute__((ext_vector_type(4))) float f32x4;

// async global->LDS, 16B per lane (dest = wave-uniform base + lane*16)
__device__ __forceinline__ void gl_lds16(const void* gsrc, void* ldst) {
  __builtin_amdgcn_global_load_lds(
      (const __attribute__((address_space(1))) unsigned int*)gsrc,
      (__attribute__((address_space(3))) unsigned int*)ldst, 16, 0, 0);
}

// bf16 split: x ~= hi + lo (RNE hi, RNE lo). Native casts -> v_cvt_pk_bf16_f32.
__device__ __forceinline__ void bsplit(float x, unsigned short& h, unsigned short& s) {
  __hip_bfloat16 hb = __float2bfloat16(x);
  float hf = __bfloat162float(hb);
  float lo = x - hf;
  __hip_bfloat16 lb = __float2bfloat16(lo);
  h = __builtin_bit_cast(unsigned short, hb);
  s = __builtin_bit_cast(unsigned short, lb);
}

// ---------------- kernel 1: masked pooling partials ----------------
__global__ void pool_kernel(const float* __restrict__ hidden,
                            const int* __restrict__ mask,
                            float* __restrict__ part_pool,   // [NCHUNK][B_][H_]
                            int* __restrict__ cntpart) {     // [NCHUNK][B_]
  int b = blockIdx.x;
  int chunk = blockIdx.y;
  int t0 = chunk * TCHUNK;
  int h4 = threadIdx.x * 4;
  const float* base = hidden + ((size_t)b * T_ + t0) * H_ + h4;
  const int* mrow = mask + (size_t)b * T_ + t0;
  float a0 = 0.f, a1 = 0.f, a2 = 0.f, a3 = 0.f;
  int mcount = 0;
#pragma unroll 4
  for (int i = 0; i < TCHUNK; ++i) {
    int mi = mrow[i];
    float m = (float)mi;
    mcount += mi;
    float4 v = *reinterpret_cast<const float4*>(base + (size_t)i * H_);
    a0 += m * v.x; a1 += m * v.y; a2 += m * v.z; a3 += m * v.w;
  }
  float* pp = part_pool + ((size_t)chunk * B_ + b) * H_ + h4;
  *reinterpret_cast<float4*>(pp) = make_float4(a0, a1, a2, a3);
  if (threadIdx.x == 0) cntpart[chunk * B_ + b] = mcount;
}

// ---------------- kernel 1b: reduce partials -> pooledT [h][b] ----------------
__global__ void pool_reduce_kernel(const float* __restrict__ part_pool,
                                   const int* __restrict__ cntpart,
                                   float* __restrict__ pooledT,
                                   int* __restrict__ cnt) {
  int g = blockIdx.x * 256 + threadIdx.x;   // g = b*1024 + h
  float s = 0.f;
  for (int c = 0; c < NCHUNK; ++c) s += part_pool[(size_t)c * (H_ * B_) + g];
  int b = g >> 10, h = g & 1023;
  pooledT[h * B_ + b] = s;
  if (g < B_) {
    int cs = 0;
    for (int c = 0; c < NCHUNK; ++c) cs += cntpart[c * B_ + g];
    cnt[g] = cs;
  }
}

// ---------------- kernel 2: pre_q = pooled @ W^T ----------------
__global__ void proj_kernel(const float* __restrict__ Wp,
                            const float* __restrict__ pooledT,
                            const int* __restrict__ cnt,
                            float* __restrict__ preq) {
  int t = threadIdx.x;
  int olocal = t >> 5;
  int o = blockIdx.x * 8 + olocal;
  int b = t & 31;
  const float* wrow = Wp + (size_t)o * H_;
  float acc = 0.f;
#pragma unroll 4
  for (int k = 0; k < H_; k += 4) {
    float4 w4 = *reinterpret_cast<const float4*>(wrow + k);
    float p0 = pooledT[(k + 0) * B_ + b];
    float p1 = pooledT[(k + 1) * B_ + b];
    float p2 = pooledT[(k + 2) * B_ + b];
    float p3 = pooledT[(k + 3) * B_ + b];
    acc += w4.x * p0 + w4.y * p1 + w4.z * p2 + w4.w * p3;
  }
  float denom = fmaxf((float)cnt[b], 1.0f);
  float val = acc / denom;
  __shared__ float xch[8][32];
  xch[olocal][b] = val;
  __syncthreads();
  int b2 = t >> 3, j = t & 7;
  preq[(size_t)b2 * OUTO + blockIdx.x * 8 + j] = xch[j][b2];
}

// ---------------- kernel 2b: split preq into swizzled MFMA bf16 image + xnorm ----------------
// A_img (ushort): [ks 0..31] { hi[256][32], lo[256][32] }, XOR-swizzled within each
// row-slab: ushort_idx ^= (row&7)<<3  (byte ^= (row&7)<<4). dist reads with same XOR.
__global__ void aprep_kernel(const float* __restrict__ preq,
                             unsigned short* __restrict__ A_img,
                             float* __restrict__ xnorm) {
  int row = blockIdx.x;
  int t = threadIdx.x;
  int k0 = 4 * t;
  int ks = k0 >> 5, kk = k0 & 31;
  float4 v = reinterpret_cast<const float4*>(preq + (size_t)row * H_)[t];
  float xv[4] = {v.x, v.y, v.z, v.w};
  unsigned short hv[4], lv[4];
  float s = 0.f;
#pragma unroll
  for (int i = 0; i < 4; ++i) { s += xv[i] * xv[i]; bsplit(xv[i], hv[i], lv[i]); }
  unsigned int sidx = (unsigned int)(row * 32 + kk) ^ (unsigned int)((row & 7) << 3);
  size_t base = (size_t)ks * 16384 + sidx;
  *reinterpret_cast<ushort4*>(&A_img[base])        = make_ushort4(hv[0], hv[1], hv[2], hv[3]);
  *reinterpret_cast<ushort4*>(&A_img[base + 8192]) = make_ushort4(lv[0], lv[1], lv[2], lv[3]);
#pragma unroll
  for (int off = 1; off < 64; off <<= 1) s += __shfl_xor(s, off);
  __shared__ float ps[4];
  if ((t & 63) == 0) ps[t >> 6] = s;
  __syncthreads();
  if (t == 0) xnorm[row] = ps[0] + ps[1] + ps[2] + ps[3];
}

// ---------------- kernel 3: split-bf16 MFMA distance GEMM ----------------
// BM=256, BN=128, BK=32; 512 threads = 8 waves (4 row-groups x 2 col-halves), grid 256.
// A: swizzled bf16 image staged async via global_load_lds (dbuf); conflict-free ds_read.
// B: f32 reg prefetch at top -> convert after MFMAs -> LDS (dbuf). One barrier/K-step.
// Inner: B-frags once, then 4 mt-chunks {A-reads(mt+1) || 12 MFMA} with setprio.
__global__ __launch_bounds__(512, 2) void dist_kernel(
    const unsigned short* __restrict__ A_img, const float* __restrict__ codebook,
    const float* __restrict__ xnorm, float* __restrict__ logits,
    float* __restrict__ pscore, int* __restrict__ pidx) {
  __shared__ __align__(16) unsigned short Asm[2][16384];    // 64 KB (swizzled image)
  __shared__ __align__(16) unsigned short Bs[2][2][128][40];// 40 KB
  __shared__ float cn[128];
  __shared__ float xns[256];
  __shared__ float bwv[2][256];
  __shared__ int   bwi[2][256];

  const int t = threadIdx.x;        // 0..511
  const int l = t & 63;
  const int w = t >> 6;             // wave 0..7
  const int cb = w & 1;             // col half
  const int m0 = (w >> 1) * 64;     // row group
  const int lr = l & 15, lq = l >> 4;
  const int blk = blockIdx.x;
  const int v0 = blk * 128;

  if (t < 256) xns[t] = xnorm[t];

  const int sn = t >> 2;            // staged codebook row 0..127
  const int sk = (t & 3) * 8;       // k offset within 32
  const float* cbp = codebook + (size_t)(v0 + sn) * H_ + sk;
  float csq = 0.f;

  f32x4 acc[4][4];
#pragma unroll
  for (int i = 0; i < 4; ++i)
#pragma unroll
    for (int j = 0; j < 4; ++j) acc[i][j] = (f32x4){0.f, 0.f, 0.f, 0.f};

  const char* Abase = (const char*)A_img;

  // per-thread swizzled A read offsets (ushort units): row = m0 + mt*16 + lr
  unsigned int aoff[4];
#pragma unroll
  for (int mt = 0; mt < 4; ++mt) {
    int row = m0 + mt * 16 + lr;
    aoff[mt] = (unsigned int)(row * 32 + lq * 8) ^ (unsigned int)((row & 7) << 3);
  }

  // ---- prologue: stage A(0) async; load+convert B(0) ----
#pragma unroll
  for (int j = 0; j < 4; ++j) {
    int c = w * 4 + j;
    gl_lds16(Abase + (size_t)c * 1024 + (size_t)l * 16, &Asm[0][c * 512]);
  }
  float4 r0 = *reinterpret_cast<const float4*>(cbp);
  float4 r1 = *reinterpret_cast<const float4*>(cbp + 4);
  {
    float xv[8] = {r0.x, r0.y, r0.z, r0.w, r1.x, r1.y, r1.z, r1.w};
    u16x8 hv, lv;
#pragma unroll
    for (int i = 0; i < 8; ++i) {
      float x = xv[i];
      csq += x * x;
      unsigned short hh, ll;
      bsplit(x, hh, ll);
      hv[i] = hh; lv[i] = ll;
    }
    *reinterpret_cast<u16x8*>(&Bs[0][0][sn][sk]) = hv;
    *reinterpret_cast<u16x8*>(&Bs[0][1][sn][sk]) = lv;
  }
  __syncthreads();

  int cur = 0;
#pragma unroll 2
  for (int ks = 0; ks < 32; ++ks) {
    // top: issue next-step loads (A async -> LDS buf^1; B f32 -> regs)
    if (ks < 31) {
#pragma unroll
      for (int j = 0; j < 4; ++j) {
        int c = w * 4 + j;
        gl_lds16(Abase + (size_t)(ks + 1) * 32768 + (size_t)c * 1024 + (size_t)l * 16,
                 &Asm[cur ^ 1][c * 512]);
      }
      r0 = *reinterpret_cast<const float4*>(cbp + (ks + 1) * 32);
      r1 = *reinterpret_cast<const float4*>(cbp + (ks + 1) * 32 + 4);
    }
    // B fragments (once per K-step)
    s16x8 bh[4], bl[4];
#pragma unroll
    for (int nt = 0; nt < 4; ++nt) {
      bh[nt] = *reinterpret_cast<const s16x8*>(&Bs[cur][0][cb * 64 + nt * 16 + lr][lq * 8]);
      bl[nt] = *reinterpret_cast<const s16x8*>(&Bs[cur][1][cb * 64 + nt * 16 + lr][lq * 8]);
    }
    // chunked A reads + MFMA: read chunk mt+1 while computing chunk mt
    s16x8 ah[4], al[4];
    {
      const unsigned short* p = &Asm[cur][aoff[0]];
      ah[0] = *reinterpret_cast<const s16x8*>(p);
      al[0] = *reinterpret_cast<const s16x8*>(p + 8192);
    }
#pragma unroll
    for (int mt = 0; mt < 4; ++mt) {
      if (mt < 3) {
        const unsigned short* p = &Asm[cur][aoff[mt + 1]];
        ah[mt + 1] = *reinterpret_cast<const s16x8*>(p);
        al[mt + 1] = *reinterpret_cast<const s16x8*>(p + 8192);
      }
      __builtin_amdgcn_s_setprio(1);
#pragma unroll
      for (int nt = 0; nt < 4; ++nt) {
        acc[mt][nt] = __builtin_amdgcn_mfma_f32_16x16x32_bf16(ah[mt], bh[nt], acc[mt][nt], 0, 0, 0);
        acc[mt][nt] = __builtin_amdgcn_mfma_f32_16x16x32_bf16(ah[mt], bl[nt], acc[mt][nt], 0, 0, 0);
        acc[mt][nt] = __builtin_amdgcn_mfma_f32_16x16x32_bf16(al[mt], bh[nt], acc[mt][nt], 0, 0, 0);
      }
      __builtin_amdgcn_s_setprio(0);
    }
    // convert next-step B (regs loaded at top; MFMA block covered the HBM latency)
    if (ks < 31) {
      float xv[8] = {r0.x, r0.y, r0.z, r0.w, r1.x, r1.y, r1.z, r1.w};
      u16x8 hv, lv;
#pragma unroll
      for (int i = 0; i < 8; ++i) {
        float x = xv[i];
        csq += x * x;
        unsigned short hh, ll;
        bsplit(x, hh, ll);
        hv[i] = hh; lv[i] = ll;
      }
      *reinterpret_cast<u16x8*>(&Bs[cur ^ 1][0][sn][sk]) = hv;
      *reinterpret_cast<u16x8*>(&Bs[cur ^ 1][1][sn][sk]) = lv;
    }
    __syncthreads();   // drains vmcnt -> A(ks+1) staged, B LDS visible
    cur ^= 1;
  }

  // ||c||^2: reduce the 4 k-offset threads (consecutive lanes) of each staged row
  csq += __shfl_xor(csq, 1);
  csq += __shfl_xor(csq, 2);
  if ((t & 3) == 0) cn[sn] = csq;
  __syncthreads();

  // epilogue: logits + per-row best over this block's 128 cols
  const float NEG = -3.402823466e38f;
#pragma unroll
  for (int mt = 0; mt < 4; ++mt) {
#pragma unroll
    for (int r = 0; r < 4; ++r) {
      int row = m0 + mt * 16 + lq * 4 + r;
      float xn = xns[row];
      float bs = NEG; int bix = 0;
#pragma unroll
      for (int nt = 0; nt < 4; ++nt) {
        int col = cb * 64 + nt * 16 + lr;
        float sc = 2.f * acc[mt][nt][r] - cn[col];
        logits[(size_t)row * V_ + v0 + col] = sc - xn;
        if (sc > bs) { bs = sc; bix = v0 + col; }   // nt ascending => first-max tie-break
      }
#pragma unroll
      for (int off = 1; off < 16; off <<= 1) {      // reduce within 16-lane (same-row) group
        float os = __shfl_xor(bs, off);
        int oi = __shfl_xor(bix, off);
        if (os > bs || (os == bs && oi < bix)) { bs = os; bix = oi; }
      }
      if (lr == 0) { bwv[cb][row] = bs; bwi[cb][row] = bix; }
    }
  }
  __syncthreads();
  if (t < 256) {
    float b0 = bwv[0][t]; int i0 = bwi[0][t];
    float b1 = bwv[1][t]; int i1 = bwi[1][t];
    if (b1 > b0 || (b1 == b0 && i1 < i0)) { b0 = b1; i0 = i1; }
    pscore[(size_t)t * NCB + blk] = b0;
    pidx[(size_t)t * NCB + blk] = i0;
  }
}

// ---------------- kernel 4: per-row argmax over blocks, gather, quantized, loss partial ----------------
__global__ void finalize_kernel(const float* __restrict__ preq,
                                const float* __restrict__ codebook,
                                const float* __restrict__ pscore,
                                const int* __restrict__ pidx,
                                float* __restrict__ out_idx,
                                float* __restrict__ out_quant,
                                float* __restrict__ lsum) {
  int row = blockIdx.x;
  int t = threadIdx.x;
  float bs = -3.402823466e38f; int bi = 0x7fffffff;
  for (int p = t; p < NCB; p += 256) {
    float s = pscore[(size_t)row * NCB + p];
    int ix = pidx[(size_t)row * NCB + p];
    if (s > bs || (s == bs && ix < bi)) { bs = s; bi = ix; }
  }
#pragma unroll
  for (int off = 1; off < 64; off <<= 1) {
    float os = __shfl_xor(bs, off);
    int oi = __shfl_xor(bi, off);
    if (os > bs || (os == bs && oi < bi)) { bs = os; bi = oi; }
  }
  __shared__ float ss[4]; __shared__ int si[4]; __shared__ int fidx;
  if ((t & 63) == 0) { ss[t >> 6] = bs; si[t >> 6] = bi; }
  __syncthreads();
  if (t == 0) {
    float b0 = ss[0]; int i0 = si[0];
    for (int wv = 1; wv < 4; ++wv)
      if (ss[wv] > b0 || (ss[wv] == b0 && si[wv] < i0)) { b0 = ss[wv]; i0 = si[wv]; }
    fidx = i0;
    out_idx[row] = (float)i0;
  }
  __syncthreads();
  int idx = fidx;
  float4 e = reinterpret_cast<const float4*>(codebook + (size_t)idx * H_)[t];
  float4 p = reinterpret_cast<const float4*>(preq + (size_t)row * H_)[t];
  float4 q;
  q.x = p.x + (e.x - p.x); q.y = p.y + (e.y - p.y);
  q.z = p.z + (e.z - p.z); q.w = p.w + (e.w - p.w);
  reinterpret_cast<float4*>(out_quant)[row * 256 + t] = q;
  float dx = p.x - e.x, dy = p.y - e.y, dz = p.z - e.z, dw = p.w - e.w;
  float ls = dx * dx + dy * dy + dz * dz + dw * dw;
#pragma unroll
  for (int off = 1; off < 64; off <<= 1) ls += __shfl_xor(ls, off);
  __shared__ float lss[4];
  if ((t & 63) == 0) lss[t >> 6] = ls;
  __syncthreads();
  if (t == 0) lsum[row] = lss[0] + lss[1] + lss[2] + lss[3];
}

// ---------------- kernel 5: final losses ----------------
__global__ void loss_kernel(const float* __restrict__ lsum, float* __restrict__ out_loss) {
  int t = threadIdx.x;
  float s = lsum[t];
#pragma unroll
  for (int off = 1; off < 64; off <<= 1) s += __shfl_xor(s, off);
  __shared__ float a[4];
  if ((t & 63) == 0) a[t >> 6] = s;
  __syncthreads();
  if (t == 0) {
    float lv = (a[0] + a[1] + a[2] + a[3]) / (float)(ROWS * H_);
    out_loss[0] = lv; out_loss[1] = lv;
  }
}

extern "C" void kernel_launch(void* const* d_in, const int* in_sizes, int n_in,
                              void* d_out, int out_size, void* d_ws, size_t ws_size,
                              hipStream_t stream) {
  (void)in_sizes; (void)n_in; (void)out_size; (void)ws_size;
  const float* hidden   = (const float*)d_in[0];
  const int* mask       = (const int*)d_in[1];
  const float* Wp       = (const float*)d_in[2];
  const float* codebook = (const float*)d_in[3];

  float* out = (float*)d_out;
  float* out_logits = out;                        // 8388608
  float* out_idx    = out + 8388608;              // 256
  float* out_preq   = out_idx + 256;              // 262144
  float* out_quant  = out_preq + 262144;          // 262144
  float* out_loss   = out_quant + 262144;         // 2

  // Early scratch inside logits region (fully overwritten by dist_kernel later).
  float* part_pool = out_logits;                   // 64*32*1024 = 2097152 floats
  int*   cntpart   = (int*)(out_logits + 2097152); // 2048
  float* pooledT   = out_logits + 2099200;         // 32768
  int*   cnt       = (int*)(out_logits + 2131968); // 32

  // d_ws scratch (~1.6 MB)
  float* ws     = (float*)d_ws;
  float* xnorm  = ws;                              // 256
  float* pscore = ws + 256;                        // 256*256
  int*   pidx   = (int*)(ws + 256 + 65536);        // 256*256
  float* lsum   = ws + 131328;                     // 256
  unsigned short* A_img = (unsigned short*)(ws + 131584);  // 1 MB

  pool_kernel<<<dim3(B_, NCHUNK), 256, 0, stream>>>(hidden, mask, part_pool, cntpart);
  pool_reduce_kernel<<<128, 256, 0, stream>>>(part_pool, cntpart, pooledT, cnt);
  proj_kernel<<<1024, 256, 0, stream>>>(Wp, pooledT, cnt, out_preq);
  aprep_kernel<<<ROWS, 256, 0, stream>>>(out_preq, A_img, xnorm);
  dist_kernel<<<NCB, 512, 0, stream>>>(A_img, codebook, xnorm, out_logits, pscore, pidx);
  finalize_kernel<<<ROWS, 256, 0, stream>>>(out_preq, codebook, pscore, pidx, out_idx, out_quant, lsum);
  loss_kernel<<<1, 256, 0, stream>>>(lsum, out_loss);
}